// Round 6
// baseline (46.608 us; speedup 1.0000x reference)
//
#include <hip/hip_runtime.h>

// Problem constants (reference: B=1, T=2048, H=32, D=64, SCALE=1/64, DEG=2)
#define T_DIM 2048
#define H_DIM 32
#define D_DIM 64
#define SCALE_F 0.015625f
#define TILE_STRIDE 2048    // ushorts per (h, 32-row frag tile) = 4KB

typedef unsigned short ushort;
typedef __attribute__((ext_vector_type(8))) short short8;   // 8 bf16
typedef __attribute__((ext_vector_type(16))) float f32x16;  // 32x32 MFMA acc
typedef __attribute__((ext_vector_type(2))) float f32x2;    // packed f32 math

// ---------------------------------------------------------------------------
// Kernel 1: per-head inclusive cumsum of g over T -> gc stored [H][T]  (B=1)
// ---------------------------------------------------------------------------
__global__ __launch_bounds__(256)
void cumsum_g_kernel(const float* __restrict__ g, float* __restrict__ gc) {
    const int h = blockIdx.x;
    const int tid = threadIdx.x;
    const int PER = T_DIM / 256;        // 8

    __shared__ float sums[256];

    float loc[8];
    float run = 0.f;
    const int t0 = tid * PER;
    for (int i = 0; i < PER; ++i) {
        run += g[(size_t)(t0 + i) * H_DIM + h];
        loc[i] = run;
    }
    sums[tid] = run;
    __syncthreads();

    for (int off = 1; off < 256; off <<= 1) {
        float vv = (tid >= off) ? sums[tid - off] : 0.f;
        __syncthreads();
        sums[tid] += vv;
        __syncthreads();
    }
    float excl = (tid == 0) ? 0.f : sums[tid - 1];

    for (int i = 0; i < PER; ++i)
        gc[(size_t)h * T_DIM + t0 + i] = excl + loc[i];
}

// ---------------------------------------------------------------------------
__device__ __forceinline__ ushort f2bf(float x) {
    unsigned u = __float_as_uint(x);
    unsigned r = (u + 0x7fffu + ((u >> 16) & 1u)) >> 16;
    return (ushort)r;
}

// ---------------------------------------------------------------------------
// Prep: frag-major bf16 buffers so ALL main-loop frag loads coalesce.
//   qfrag/kfrag: [h][t32][ks(4)][hi(2)][l31(32)][8]  content q̂/k̂[32*t32+l31][16ks+8hi+j]
//   vfrag:       [h][s32][dblk(2)][kh2(2)][hi(2)][l31(32)][8]
//                 content v̂[32*s32+16kh2+8hi+j][32dblk+l31]
// q̂ = q*SCALE*exp(gc/2), k̂ = k*exp(-gc/2), v̂ = bf16(v).
// Grid (H, T/64) so bid%8 == h%8 — frags produced on consumer's XCD L2.
// ---------------------------------------------------------------------------
__global__ __launch_bounds__(256)
void prep_kernel(const float* __restrict__ q, const float* __restrict__ k,
                 const float* __restrict__ v, const float* __restrict__ gc,
                 ushort* __restrict__ qfrag, ushort* __restrict__ kfrag,
                 ushort* __restrict__ vfrag) {
    __shared__ ushort qt_l[64 * 64];   // swizzled [row][slot] 16B chunks
    __shared__ ushort kt_l[64 * 64];

    const int h   = blockIdx.x;
    const int tt  = blockIdx.y;        // 64-row chunk
    const int tid = threadIdx.x;

    // ---- stage q̂,k̂ rows into swizzled LDS (coalesced f32 reads) ----
    {
        const int r    = tid >> 2;          // 0..63
        const int dseg = (tid & 3) * 16;    // 16 floats
        const int t    = tt * 64 + r;
        const float gct = gc[(size_t)h * T_DIM + t];
        const float eq = SCALE_F * __expf(0.5f * gct);
        const float ek = __expf(-0.5f * gct);
        const float* qp = q + ((size_t)t * H_DIM + h) * 64 + dseg;
        const float* kp = k + ((size_t)t * H_DIM + h) * 64 + dseg;
        union { ushort u[16]; uint4 uu[2]; } oq, ok;
#pragma unroll
        for (int i = 0; i < 16; ++i) {
            oq.u[i] = f2bf(qp[i] * eq);
            ok.u[i] = f2bf(kp[i] * ek);
        }
        const int c0 = (tid & 3) * 2;       // 16B chunk index base
#pragma unroll
        for (int cc = 0; cc < 2; ++cc) {
            const int slot = (c0 + cc) ^ (r & 7);
            *reinterpret_cast<uint4*>(&qt_l[r * 64 + slot * 8]) = oq.uu[cc];
            *reinterpret_cast<uint4*>(&kt_l[r * 64 + slot * 8]) = ok.uu[cc];
        }
    }
    __syncthreads();

    // ---- q/k frag writes: 512 16B-chunks each, coalesced stores ----
#pragma unroll
    for (int n = 0; n < 2; ++n) {
        const int ch   = tid + 256 * n;     // 0..511
        const int l31  = ch & 31;
        const int hi   = (ch >> 5) & 1;
        const int ks   = (ch >> 6) & 3;
        const int t32r = ch >> 8;           // 0/1
        const int row  = t32r * 32 + l31;
        const int slot = (2 * ks + hi) ^ (row & 7);
        uint4 qq = *reinterpret_cast<const uint4*>(&qt_l[row * 64 + slot * 8]);
        uint4 kk = *reinterpret_cast<const uint4*>(&kt_l[row * 64 + slot * 8]);
        const size_t base = ((size_t)h * 64 + tt * 2 + t32r) * TILE_STRIDE
                          + (size_t)(((ks * 2 + hi) * 32) + l31) * 8;
        *reinterpret_cast<uint4*>(qfrag + base) = qq;
        *reinterpret_cast<uint4*>(kfrag + base) = kk;
    }

    // ---- v frags: direct global gather (all loads/stores coalesced) ----
#pragma unroll
    for (int n = 0; n < 2; ++n) {
        const int c9   = (tid >> 5) + 8 * n;  // 0..15
        const int l31  = tid & 31;
        const int hi   = c9 & 1;
        const int kh2  = (c9 >> 1) & 1;
        const int dblk = (c9 >> 2) & 1;
        const int s32r = c9 >> 3;
        const int tb = tt * 64 + s32r * 32 + kh2 * 16 + hi * 8;
        union { ushort u[8]; uint4 uu; } ov;
#pragma unroll
        for (int j = 0; j < 8; ++j)
            ov.u[j] = f2bf(v[((size_t)(tb + j) * H_DIM + h) * 64 + dblk * 32 + l31]);
        const size_t base = ((size_t)h * 64 + tt * 2 + s32r) * TILE_STRIDE
                          + (size_t)((((dblk * 2 + kh2) * 2 + hi) * 32) + l31) * 8;
        *reinterpret_cast<uint4*>(vfrag + base) = ov.uu;
    }
}

// ---------------------------------------------------------------------------
// Main kernel helpers
// ---------------------------------------------------------------------------
__device__ __forceinline__ short8 ld8(const ushort* p) {
    return *reinterpret_cast<const short8*>(p);
}

__device__ __forceinline__ unsigned cvt_pk_bf16(float lo, float hi) {
    unsigned r;
    asm("v_cvt_pk_bf16_f32 %0, %1, %2" : "=v"(r) : "v"(lo), "v"(hi));
    return r;
}

// Pack 8 f32 W-values (4 f32x2 pairs, C-layout half) into the PV A-operand
// fragment via cvt_pk + permlane32_swap. (Layout verified R3/R4.)
__device__ __forceinline__ short8 pack_w2(const f32x2* w2) {
    unsigned p0 = cvt_pk_bf16(w2[0][0], w2[0][1]);
    unsigned p1 = cvt_pk_bf16(w2[1][0], w2[1][1]);
    unsigned p2 = cvt_pk_bf16(w2[2][0], w2[2][1]);
    unsigned p3 = cvt_pk_bf16(w2[3][0], w2[3][1]);
    asm("v_permlane32_swap_b32 %0, %1" : "+v"(p0), "+v"(p2));
    asm("v_permlane32_swap_b32 %0, %1" : "+v"(p1), "+v"(p3));
    union { unsigned u[4]; short8 s; } af;
    af.u[0] = p0; af.u[1] = p1; af.u[2] = p2; af.u[3] = p3;
    return af.s;
}

// K/V fragment set for one 32-s step (8 coalesced dwordx4 loads).
struct Frags {
    short8 k0, k1, k2, k3;
    short8 v0, v1, v2, v3;   // v0=dblk0/kh2=0, v1=dblk0/kh2=1, v2=dblk1/kh2=0, v3=dblk1/kh2=1
};

__device__ __forceinline__ void load_frags(Frags& f, const ushort* kb,
                                           const ushort* vb, int lofs) {
    f.v0 = ld8(vb + lofs);
    f.v1 = ld8(vb + 512 + lofs);
    f.v2 = ld8(vb + 1024 + lofs);
    f.v3 = ld8(vb + 1536 + lofs);
    f.k0 = ld8(kb + lofs);
    f.k1 = ld8(kb + 512 + lofs);
    f.k2 = ld8(kb + 1024 + lofs);
    f.k3 = ld8(kb + 1536 + lofs);
}

// Compute one 32-s step against the 64-col q-tile (halves L/H).
// MODE 0: both full | 1: L diag, H full | 2: L skip, H diag.
template<int MODE>
__device__ __forceinline__ void compute64(
    const Frags& f, int hi, int l31,
    const short8 (&qrL)[4], const short8 (&qrH)[4],
    f32x16& o00, f32x16& o01, f32x16& o10, f32x16& o11,
    f32x2& den2L, f32x2& den2H)
{
    f32x16 cH;
#pragma unroll
    for (int i = 0; i < 16; ++i) cH[i] = 0.f;
    f32x16 cL = cH;

    if (MODE <= 1) {
        cL = __builtin_amdgcn_mfma_f32_32x32x16_bf16(f.k0, qrL[0], cL, 0, 0, 0);
        cH = __builtin_amdgcn_mfma_f32_32x32x16_bf16(f.k0, qrH[0], cH, 0, 0, 0);
        cL = __builtin_amdgcn_mfma_f32_32x32x16_bf16(f.k1, qrL[1], cL, 0, 0, 0);
        cH = __builtin_amdgcn_mfma_f32_32x32x16_bf16(f.k1, qrH[1], cH, 0, 0, 0);
        cL = __builtin_amdgcn_mfma_f32_32x32x16_bf16(f.k2, qrL[2], cL, 0, 0, 0);
        cH = __builtin_amdgcn_mfma_f32_32x32x16_bf16(f.k2, qrH[2], cH, 0, 0, 0);
        cL = __builtin_amdgcn_mfma_f32_32x32x16_bf16(f.k3, qrL[3], cL, 0, 0, 0);
        cH = __builtin_amdgcn_mfma_f32_32x32x16_bf16(f.k3, qrH[3], cH, 0, 0, 0);
    } else {
        cH = __builtin_amdgcn_mfma_f32_32x32x16_bf16(f.k0, qrH[0], cH, 0, 0, 0);
        cH = __builtin_amdgcn_mfma_f32_32x32x16_bf16(f.k1, qrH[1], cH, 0, 0, 0);
        cH = __builtin_amdgcn_mfma_f32_32x32x16_bf16(f.k2, qrH[2], cH, 0, 0, 0);
        cH = __builtin_amdgcn_mfma_f32_32x32x16_bf16(f.k3, qrH[3], cH, 0, 0, 0);
    }

    // square (+mask) + denom via packed f32 pairs
    f32x2 wL[8], wH[8];
#pragma unroll
    for (int i = 0; i < 8; ++i) {
        const int r0 = 2 * i, r1 = 2 * i + 1;
        const int sl0 = (r0 & 3) + 8 * (r0 >> 2) + 4 * hi;
        const int sl1 = (r1 & 3) + 8 * (r1 >> 2) + 4 * hi;
        f32x2 x; x[0] = cH[r0]; x[1] = cH[r1];
        f32x2 ww = x * x;
        if (MODE == 2) {
            ww[0] = (sl0 <= l31) ? ww[0] : 0.f;
            ww[1] = (sl1 <= l31) ? ww[1] : 0.f;
        }
        wH[i] = ww;
        den2H += ww;
        if (MODE <= 1) {
            f32x2 y; y[0] = cL[r0]; y[1] = cL[r1];
            f32x2 wwl = y * y;
            if (MODE == 1) {
                wwl[0] = (sl0 <= l31) ? wwl[0] : 0.f;
                wwl[1] = (sl1 <= l31) ? wwl[1] : 0.f;
            }
            wL[i] = wwl;
            den2L += wwl;
        }
    }

    if (MODE <= 1) {
        const short8 a0 = pack_w2(&wL[0]);
        o00 = __builtin_amdgcn_mfma_f32_32x32x16_bf16(a0, f.v0, o00, 0, 0, 0);
        o01 = __builtin_amdgcn_mfma_f32_32x32x16_bf16(a0, f.v2, o01, 0, 0, 0);
        const short8 a1 = pack_w2(&wL[4]);
        o00 = __builtin_amdgcn_mfma_f32_32x32x16_bf16(a1, f.v1, o00, 0, 0, 0);
        o01 = __builtin_amdgcn_mfma_f32_32x32x16_bf16(a1, f.v3, o01, 0, 0, 0);
    }
    {
        const short8 b0 = pack_w2(&wH[0]);
        o10 = __builtin_amdgcn_mfma_f32_32x32x16_bf16(b0, f.v0, o10, 0, 0, 0);
        o11 = __builtin_amdgcn_mfma_f32_32x32x16_bf16(b0, f.v2, o11, 0, 0, 0);
        const short8 b1 = pack_w2(&wH[4]);
        o10 = __builtin_amdgcn_mfma_f32_32x32x16_bf16(b1, f.v1, o10, 0, 0, 0);
        o11 = __builtin_amdgcn_mfma_f32_32x32x16_bf16(b1, f.v3, o11, 0, 0, 0);
    }
}

// Epilogue phase for one t-half: LDS-reduce 4 waves' partials + write out.
__device__ __forceinline__ void epi_phase(
    int thalf, const f32x16& od0, const f32x16& od1,
    int t0, int h, int w, int hi, int l31,
    float* __restrict__ out, float* lds_o, const float* lds_den)
{
    __syncthreads();
#pragma unroll
    for (int r = 0; r < 16; ++r) {
        const int row = (r & 3) + 8 * (r >> 2) + 4 * hi;
        lds_o[((w * 2 + 0) * 32 + row) * 32 + l31] = od0[r];
        lds_o[((w * 2 + 1) * 32 + row) * 32 + l31] = od1[r];
    }
    __syncthreads();
#pragma unroll
    for (int rr = 0; rr < 8; ++rr) {
        const int row = 8 * w + rr;
        const float s = lds_o[((0 + hi) * 32 + row) * 32 + l31]
                      + lds_o[((2 + hi) * 32 + row) * 32 + l31]
                      + lds_o[((4 + hi) * 32 + row) * 32 + l31]
                      + lds_o[((6 + hi) * 32 + row) * 32 + l31];
        const float dt = lds_den[(0 + thalf) * 32 + row]
                       + lds_den[(2 + thalf) * 32 + row]
                       + lds_den[(4 + thalf) * 32 + row]
                       + lds_den[(6 + thalf) * 32 + row];
        const float inv = 1.f / fmaxf(dt, 1.f);
        out[((size_t)(t0 + thalf * 32 + row) * H_DIM + h) * 64 + hi * 32 + l31]
            = s * inv;
    }
}

// Process one 64-row q-tile tt. 4 waves split-K over 32-row s-steps,
// software-pipelined (ping-pong frag registers).
__device__ __forceinline__ void process_tile64(
    int tt, int h, int w, int hi, int l31, int lofs,
    const ushort* __restrict__ qfrag, const ushort* __restrict__ kfrag,
    const ushort* __restrict__ vfrag, float* __restrict__ out,
    float* lds_o, float* lds_den)
{
    short8 qrL[4], qrH[4];
    const ushort* qb = qfrag + ((size_t)h * 64 + 2 * tt) * TILE_STRIDE;
#pragma unroll
    for (int ks = 0; ks < 4; ++ks) {
        qrL[ks] = ld8(qb + ks * 512 + lofs);
        qrH[ks] = ld8(qb + TILE_STRIDE + ks * 512 + lofs);
    }

    f32x16 o00, o01, o10, o11;
#pragma unroll
    for (int i = 0; i < 16; ++i) { o00[i] = 0.f; o01[i] = 0.f; o10[i] = 0.f; o11[i] = 0.f; }
    f32x2 den2L, den2H;
    den2L[0] = 0.f; den2L[1] = 0.f; den2H[0] = 0.f; den2H[1] = 0.f;

    const ushort* kh_b = kfrag + (size_t)h * 64 * TILE_STRIDE;
    const ushort* vh_b = vfrag + (size_t)h * 64 * TILE_STRIDE;
    const int dlo = 2 * tt;

    // --- pipelined full steps: st = w, w+4, ... < dlo ---
    Frags fA, fB;
    int st = w;
    if (st < dlo)
        load_frags(fA, kh_b + (size_t)st * TILE_STRIDE, vh_b + (size_t)st * TILE_STRIDE, lofs);
    for (; st + 4 < dlo; st += 8) {
        load_frags(fB, kh_b + (size_t)(st + 4) * TILE_STRIDE,
                   vh_b + (size_t)(st + 4) * TILE_STRIDE, lofs);
        compute64<0>(fA, hi, l31, qrL, qrH, o00, o01, o10, o11, den2L, den2H);
        if (st + 8 < dlo)
            load_frags(fA, kh_b + (size_t)(st + 8) * TILE_STRIDE,
                       vh_b + (size_t)(st + 8) * TILE_STRIDE, lofs);
        compute64<0>(fB, hi, l31, qrL, qrH, o00, o01, o10, o11, den2L, den2H);
    }
    if (st < dlo)
        compute64<0>(fA, hi, l31, qrL, qrH, o00, o01, o10, o11, den2L, den2H);

    // --- boundary (diagonal) steps ---
    if ((dlo & 3) == w) {
        load_frags(fA, kh_b + (size_t)dlo * TILE_STRIDE, vh_b + (size_t)dlo * TILE_STRIDE, lofs);
        compute64<1>(fA, hi, l31, qrL, qrH, o00, o01, o10, o11, den2L, den2H);
    }
    if (((dlo + 1) & 3) == w) {
        load_frags(fA, kh_b + (size_t)(dlo + 1) * TILE_STRIDE,
                   vh_b + (size_t)(dlo + 1) * TILE_STRIDE, lofs);
        compute64<2>(fA, hi, l31, qrL, qrH, o00, o01, o10, o11, den2L, den2H);
    }

    float denL = den2L[0] + den2L[1];
    float denH = den2H[0] + den2H[1];
    denL += __shfl_xor(denL, 32);
    denH += __shfl_xor(denH, 32);
    if (hi == 0) {
        lds_den[(w * 2 + 0) * 32 + l31] = denL;   // t-half 0, t-col l31
        lds_den[(w * 2 + 1) * 32 + l31] = denH;   // t-half 1
    }

    const int t0 = tt * 64;
    epi_phase(0, o00, o01, t0, h, w, hi, l31, out, lds_o, lds_den);
    epi_phase(1, o10, o11, t0, h, w, hi, l31, out, lds_o, lds_den);
}

// ---------------------------------------------------------------------------
// Kernel 3: grid 512 = 16 pairs x 32 heads (h = bid&31 -> head-home XCD).
// Block handles 64-row q-tiles (31-p) then (p): uniform 68 s-steps.
// ---------------------------------------------------------------------------
__global__ __launch_bounds__(256, 2)
void retention_mfma_kernel(const ushort* __restrict__ qfrag,
                           const ushort* __restrict__ kfrag,
                           const ushort* __restrict__ vfrag,
                           float* __restrict__ out) {
    __shared__ float lds_o[4 * 2 * 32 * 32];   // 32 KB
    __shared__ float lds_den[4 * 2 * 32];      // 1 KB

    const int bid = blockIdx.x;
    const int p   = bid >> 5;          // pair 0..15
    const int h   = bid & 31;          // head fastest -> head-home XCD
    const int lane = threadIdx.x & 63;
    const int w    = threadIdx.x >> 6; // wave 0..3 (split-K role)
    const int hi   = lane >> 5;
    const int l31  = lane & 31;
    const int lofs = hi * 256 + l31 * 8;

    process_tile64(31 - p, h, w, hi, l31, lofs, qfrag, kfrag, vfrag, out, lds_o, lds_den);
    process_tile64(p,      h, w, hi, l31, lofs, qfrag, kfrag, vfrag, out, lds_o, lds_den);
}

// ---------------------------------------------------------------------------
extern "C" void kernel_launch(void* const* d_in, const int* in_sizes, int n_in,
                              void* d_out, int out_size, void* d_ws, size_t ws_size,
                              hipStream_t stream) {
    const float* q = (const float*)d_in[0];
    const float* k = (const float*)d_in[1];
    const float* v = (const float*)d_in[2];
    const float* g = (const float*)d_in[3];
    float* out = (float*)d_out;

    const size_t GC_BYTES = (size_t)H_DIM * T_DIM * sizeof(float);   // 256 KB
    const size_t BF_ELEMS = (size_t)H_DIM * T_DIM * D_DIM;           // 4.2M ushorts

    float* gc = (float*)d_ws;
    ushort* qfrag = (ushort*)((char*)d_ws + GC_BYTES);
    ushort* kfrag = qfrag + BF_ELEMS;
    ushort* vfrag = kfrag + BF_ELEMS;

    cumsum_g_kernel<<<H_DIM, 256, 0, stream>>>(g, gc);
    prep_kernel<<<dim3(H_DIM, T_DIM / 64), 256, 0, stream>>>(q, k, v, gc,
                                                             qfrag, kfrag, vfrag);
    retention_mfma_kernel<<<16 * H_DIM, 256, 0, stream>>>(qfrag, kfrag, vfrag, out);
}